// Round 1
// baseline (338.203 us; speedup 1.0000x reference)
//
#include <hip/hip_runtime.h>
#include <hip/hip_bf16.h>

#define N_EDGES 800000
#define M_BLK   64
#define NBLK    (N_EDGES / M_BLK)   // 12500
#define XS      200                  // X LDS row stride (f16 elems), 192 used
#define HS      136                  // H LDS row stride (f16 elems), 128 used

typedef __attribute__((ext_vector_type(8))) _Float16 half8;
typedef __attribute__((ext_vector_type(4))) float    f32x4;

// ---------------- weight prep: transpose + fp32->fp16 ----------------
// ws layout (bytes):
//   0       wt1s  [128][192] f16   (49152)
//   49152   wt1v  [128][192] f16   (49152)
//   98304   wt2s  [64][128]  f16   (16384)
//   114688  wt2v  [32][128]  f16   (8192)
//   122880  w1s192[128] f32        (512)
//   123392  w1v192[128] f32        (512)
__global__ void prep_kernel(const float* __restrict__ W1s, const float* __restrict__ W1v,
                            const float* __restrict__ W2s, const float* __restrict__ W2v,
                            _Float16* __restrict__ wt1s, _Float16* __restrict__ wt1v,
                            _Float16* __restrict__ wt2s, _Float16* __restrict__ wt2v,
                            float* __restrict__ w1s192, float* __restrict__ w1v192)
{
    int idx = blockIdx.x * blockDim.x + threadIdx.x;
    if (idx < 128 * 192) {
        int c = idx / 192, k = idx % 192;
        wt1s[idx] = (_Float16)W1s[k * 128 + c];
        wt1v[idx] = (_Float16)W1v[k * 128 + c];
        return;
    }
    int i2 = idx - 128 * 192;
    if (i2 >= 0 && i2 < 64 * 128) {
        int c = i2 / 128, k = i2 % 128;
        wt2s[i2] = (_Float16)W2s[k * 64 + c];
        return;
    }
    int i3 = idx - (128 * 192 + 64 * 128);
    if (i3 >= 0 && i3 < 32 * 128) {
        int c = i3 / 128, k = i3 % 128;
        wt2v[i3] = (_Float16)W2v[k * 32 + c];
        return;
    }
    int i4 = idx - (128 * 192 + 64 * 128 + 32 * 128);
    if (i4 >= 0 && i4 < 128) {
        w1s192[i4] = W1s[192 * 128 + i4];
        w1v192[i4] = W1v[192 * 128 + i4];
    }
}

// ---------------- fused edge-MLP kernel ----------------
// block = 512 threads (8 waves), M_BLK = 64 edges per block.
// layer1: X[64][192]f16 @ W1{s,v}[192][128] -> H{s,v}[64][128] (each wave owns a
//         16-col stripe, MFMA 16x16x32 f16, K=192 -> 6 ksteps)
// layer2: Hs @ W2s -> h0[64][64]; Hv @ W2v -> amp[64][32] -> v0
__global__ __launch_bounds__(512) void edge_mlp_kernel(
    const int*   __restrict__ endpoints,
    const float* __restrict__ edge_len,
    const float* __restrict__ theta,
    const float* __restrict__ feat,
    const float* __restrict__ b1s, const float* __restrict__ b2s,
    const float* __restrict__ b1v, const float* __restrict__ b2v,
    const _Float16* __restrict__ wt1s, const _Float16* __restrict__ wt1v,
    const _Float16* __restrict__ wt2s, const _Float16* __restrict__ wt2v,
    const float* __restrict__ w1s192, const float* __restrict__ w1v192,
    float* __restrict__ h0, float* __restrict__ v0)
{
    __shared__ _Float16 ldsX[M_BLK * XS];    // reused as Hv after layer 1
    __shared__ _Float16 ldsHs[M_BLK * HS];
    __shared__ float    ldsLen[M_BLK];
    __shared__ float2   ldsDir[M_BLK];

    const int t   = threadIdx.x;
    const int blk = blockIdx.x;
    const int w   = t >> 6;     // wave 0..7
    const int l   = t & 63;
    const int lr  = l & 15;     // "row/col" lane index inside fragment
    const int lk  = l >> 4;     // k-group 0..3

    // ---- B-fragment prefetch for layer 1 (global, L2-resident) ----
    const int c1 = w * 16 + lr;             // hidden column owned by this lane
    half8 bs[6], bv[6];
#pragma unroll
    for (int ks = 0; ks < 6; ++ks) {
        bs[ks] = *reinterpret_cast<const half8*>(wt1s + c1 * 192 + ks * 32 + lk * 8);
        bv[ks] = *reinterpret_cast<const half8*>(wt1v + c1 * 192 + ks * 32 + lk * 8);
    }

    // ---- stage X (gather + diff + f16 convert) ----
    {
        const int e  = t >> 3;           // edge within block: 0..63
        const int f0 = (t & 7) * 8;      // feature offset: 0,8,...,56
        const int ge = blk * M_BLK + e;
        const int vi = endpoints[2 * ge];
        const int vj = endpoints[2 * ge + 1];
        const float4* fi = reinterpret_cast<const float4*>(feat + (size_t)vi * 64 + f0);
        const float4* fj = reinterpret_cast<const float4*>(feat + (size_t)vj * 64 + f0);
        float4 a0 = fi[0], a1 = fi[1];
        float4 b0 = fj[0], b1 = fj[1];
        float ai[8] = {a0.x, a0.y, a0.z, a0.w, a1.x, a1.y, a1.z, a1.w};
        float bj[8] = {b0.x, b0.y, b0.z, b0.w, b1.x, b1.y, b1.z, b1.w};
        half8 pi, pj, pd;
#pragma unroll
        for (int q = 0; q < 8; ++q) {
            pi[q] = (_Float16)ai[q];
            pj[q] = (_Float16)bj[q];
            pd[q] = (_Float16)fabsf(ai[q] - bj[q]);
        }
        *reinterpret_cast<half8*>(&ldsX[e * XS + f0])       = pi;
        *reinterpret_cast<half8*>(&ldsX[e * XS + 64 + f0])  = pj;
        *reinterpret_cast<half8*>(&ldsX[e * XS + 128 + f0]) = pd;

        if (t < M_BLK) {
            ldsLen[t] = edge_len[blk * M_BLK + t];
        } else if (t < 2 * M_BLK) {
            int ee = t - M_BLK;
            float th = theta[blk * M_BLK + ee];
            ldsDir[ee] = make_float2(cosf(th), sinf(th));
        }
    }
    __syncthreads();

    // ---- layer 1 MFMA: each wave computes H[64 rows][16-col stripe] for BOTH MLPs
    f32x4 accs[4], accv[4];
#pragma unroll
    for (int rt = 0; rt < 4; ++rt) {
        accs[rt] = (f32x4){0.f, 0.f, 0.f, 0.f};
        accv[rt] = (f32x4){0.f, 0.f, 0.f, 0.f};
    }
#pragma unroll
    for (int rt = 0; rt < 4; ++rt) {
#pragma unroll
        for (int ks = 0; ks < 6; ++ks) {
            half8 a = *reinterpret_cast<const half8*>(&ldsX[(rt * 16 + lr) * XS + ks * 32 + lk * 8]);
            accs[rt] = __builtin_amdgcn_mfma_f32_16x16x32_f16(a, bs[ks], accs[rt], 0, 0, 0);
            accv[rt] = __builtin_amdgcn_mfma_f32_16x16x32_f16(a, bv[ks], accv[rt], 0, 0, 0);
        }
    }

    // ---- layer 1 epilogue: + bias + len*W1[192,:] (fp32), relu, f16 -> LDS
    const float b1s_c   = b1s[c1];
    const float b1v_c   = b1v[c1];
    const float w192s_c = w1s192[c1];
    const float w192v_c = w1v192[c1];
    __syncthreads();                      // all X reads done; ldsX reusable as Hv
    _Float16* ldsHv = ldsX;
#pragma unroll
    for (int rt = 0; rt < 4; ++rt) {
#pragma unroll
        for (int r = 0; r < 4; ++r) {
            int row = rt * 16 + lk * 4 + r;
            float len = ldsLen[row];
            float hs = accs[rt][r] + b1s_c + len * w192s_c;
            float hv = accv[rt][r] + b1v_c + len * w192v_c;
            ldsHs[row * HS + c1] = (_Float16)fmaxf(hs, 0.f);
            ldsHv[row * HS + c1] = (_Float16)fmaxf(hv, 0.f);
        }
    }
    __syncthreads();

    // ---- layer 2: wave (rt2,ch) owns rows rt2*16..+16, col-half ch
    const int rt2 = w >> 1;
    const int ch  = w & 1;

    // scalar head: cols ch*32 + ct*16 + lr  (64 cols total)
    half8 a2[4];
#pragma unroll
    for (int ks = 0; ks < 4; ++ks)
        a2[ks] = *reinterpret_cast<const half8*>(&ldsHs[(rt2 * 16 + lr) * HS + ks * 32 + lk * 8]);
    f32x4 acc2[2];
    acc2[0] = (f32x4){0.f, 0.f, 0.f, 0.f};
    acc2[1] = (f32x4){0.f, 0.f, 0.f, 0.f};
#pragma unroll
    for (int ct = 0; ct < 2; ++ct) {
        int c2 = ch * 32 + ct * 16 + lr;
#pragma unroll
        for (int ks = 0; ks < 4; ++ks) {
            half8 b = *reinterpret_cast<const half8*>(wt2s + c2 * 128 + ks * 32 + lk * 8);
            acc2[ct] = __builtin_amdgcn_mfma_f32_16x16x32_f16(a2[ks], b, acc2[ct], 0, 0, 0);
        }
    }
#pragma unroll
    for (int ct = 0; ct < 2; ++ct) {
        int c2 = ch * 32 + ct * 16 + lr;
        float bias = b2s[c2];
#pragma unroll
        for (int r = 0; r < 4; ++r) {
            int row = rt2 * 16 + lk * 4 + r;
            h0[(size_t)(blk * M_BLK + row) * 64 + c2] = acc2[ct][r] + bias;
        }
    }

    // vector head: cols ch*16 + lr (32 cols total), then v0 = amp * [cos, sin]
    f32x4 accV = (f32x4){0.f, 0.f, 0.f, 0.f};
    const int cv = ch * 16 + lr;
#pragma unroll
    for (int ks = 0; ks < 4; ++ks) {
        half8 a = *reinterpret_cast<const half8*>(&ldsHv[(rt2 * 16 + lr) * HS + ks * 32 + lk * 8]);
        half8 b = *reinterpret_cast<const half8*>(wt2v + cv * 128 + ks * 32 + lk * 8);
        accV = __builtin_amdgcn_mfma_f32_16x16x32_f16(a, b, accV, 0, 0, 0);
    }
    const float biasv = b2v[cv];
#pragma unroll
    for (int r = 0; r < 4; ++r) {
        int row = rt2 * 16 + lk * 4 + r;
        float amp = accV[r] + biasv;
        float2 d = ldsDir[row];
        *reinterpret_cast<float2*>(v0 + ((size_t)(blk * M_BLK + row) * 32 + cv) * 2) =
            make_float2(amp * d.x, amp * d.y);
    }
}

extern "C" void kernel_launch(void* const* d_in, const int* in_sizes, int n_in,
                              void* d_out, int out_size, void* d_ws, size_t ws_size,
                              hipStream_t stream)
{
    const int*   endpoints = (const int*)d_in[0];
    const float* edge_len  = (const float*)d_in[1];
    const float* theta     = (const float*)d_in[2];
    const float* feat      = (const float*)d_in[3];
    const float* W1s       = (const float*)d_in[4];
    const float* b1s       = (const float*)d_in[5];
    const float* W2s       = (const float*)d_in[6];
    const float* b2s       = (const float*)d_in[7];
    const float* W1v       = (const float*)d_in[8];
    const float* b1v       = (const float*)d_in[9];
    const float* W2v       = (const float*)d_in[10];
    const float* b2v       = (const float*)d_in[11];

    char* ws = (char*)d_ws;
    _Float16* wt1s   = (_Float16*)(ws);
    _Float16* wt1v   = (_Float16*)(ws + 49152);
    _Float16* wt2s   = (_Float16*)(ws + 98304);
    _Float16* wt2v   = (_Float16*)(ws + 114688);
    float*    w1s192 = (float*)(ws + 122880);
    float*    w1v192 = (float*)(ws + 123392);

    prep_kernel<<<145, 256, 0, stream>>>(W1s, W1v, W2s, W2v,
                                         wt1s, wt1v, wt2s, wt2v, w1s192, w1v192);

    float* h0 = (float*)d_out;
    float* v0 = h0 + (size_t)N_EDGES * 64;
    edge_mlp_kernel<<<NBLK, 512, 0, stream>>>(endpoints, edge_len, theta, feat,
                                              b1s, b2s, b1v, b2v,
                                              wt1s, wt1v, wt2s, wt2v,
                                              w1s192, w1v192, h0, v0);
}